// Round 1
// baseline (93.034 us; speedup 1.0000x reference)
//
#include <hip/hip_runtime.h>
#include <cstdint>
#include <cstddef>

typedef _Float16 f16;
typedef f16 f16x8 __attribute__((ext_vector_type(8)));
typedef f16 f16x4 __attribute__((ext_vector_type(4)));
typedef float floatx4 __attribute__((ext_vector_type(4)));

#define GAS __attribute__((address_space(1)))
#define LAS __attribute__((address_space(3)))

static constexpr int LSEQ = 2048;
static constexpr int NH   = 8;
static constexpr int DH   = 64;
static constexpr int DM   = 512;
static constexpr int WIN  = 64;
static constexpr int MR   = 4 * LSEQ;  // 8192 rows (B*L)

// ---------------------------------------------------------------- cast x -> f16
__global__ __launch_bounds__(256) void cast_x_kernel(const float* __restrict__ x,
                                                     f16* __restrict__ xb) {
    int i = blockIdx.x * 256 + threadIdx.x;      // each thread: 4 elements
    float4 v = ((const float4*)x)[i];
    f16x4 o = { (f16)v.x, (f16)v.y, (f16)v.z, (f16)v.w };
    ((f16x4*)xb)[i] = o;
}

// ------------------------------------------------- transpose W (512x512) -> Wt f16
__global__ void wt_kernel(const float* __restrict__ Wq, const float* __restrict__ Wk,
                          const float* __restrict__ Wv, const float* __restrict__ Wo,
                          f16* __restrict__ wt) {
    __shared__ float tile[32][33];
    int z = blockIdx.z;
    const float* W = z == 0 ? Wq : z == 1 ? Wk : z == 2 ? Wv : Wo;
    f16* out = wt + (size_t)z * DM * DM;
    int c0 = blockIdx.x * 32, r0 = blockIdx.y * 32;
    int tx = threadIdx.x, ty = threadIdx.y;   // block (32, 8)
    #pragma unroll
    for (int i = 0; i < 32; i += 8)
        tile[ty + i][tx] = W[(size_t)(r0 + ty + i) * DM + c0 + tx];
    __syncthreads();
    #pragma unroll
    for (int i = 0; i < 32; i += 8)
        out[(size_t)(c0 + ty + i) * DM + r0 + tx] = (f16)tile[tx][ty + i];
}

// ---------------------------------------------------------------- GEMM 128x128, BK=64
// A: [8192][512] f16 row-major.  Bt: [512][512] f16 = B^T (row = out col).
// QKV=true: blockIdx.z selects q/k/v epilogue. QKV=false: fp32 out.
template <bool QKV>
__global__ __launch_bounds__(256) void gemm_kernel(
    const f16* __restrict__ A, const f16* __restrict__ Bt_base,
    const float* __restrict__ b0, const float* __restrict__ b1,
    const float* __restrict__ b2,
    f16* __restrict__ out_q, f16* __restrict__ out_k, f16* __restrict__ out_vt,
    float* __restrict__ out_f) {
    const int z = QKV ? blockIdx.z : 0;
    const f16* __restrict__ Bt = Bt_base + (size_t)z * (DM * DM);
    const float* __restrict__ bias = QKV ? (z == 0 ? b0 : z == 1 ? b1 : b2) : b0;

    __shared__ f16 As[128 * 64];
    __shared__ f16 Bs[128 * 64];

    const int tid  = threadIdx.x;
    const int wid  = tid >> 6;
    const int lane = tid & 63;
    const int l15  = lane & 15;
    const int l4   = lane >> 4;
    const int m0   = blockIdx.y * 128;
    const int n0   = blockIdx.x * 128;
    const int wr   = wid >> 1, wc = wid & 1;

    floatx4 acc[4][4] = {};

    for (int k0 = 0; k0 < DM; k0 += 64) {
        // stage A,B tiles: 1024 chunks of 16B each; XOR-swizzled SOURCE (rule #21),
        // linear LDS dest (global_load_lds writes base + lane*16).
        #pragma unroll
        for (int i = 0; i < 4; ++i) {
            int c   = i * 256 + wid * 64 + lane;
            int row = c >> 3, cw = c & 7;
            int cs  = cw ^ (row & 7);
            const f16* ga = A  + (size_t)(m0 + row) * DM + k0 + cs * 8;
            const f16* gb = Bt + (size_t)(n0 + row) * DM + k0 + cs * 8;
            f16* la = &As[(i * 256 + wid * 64) * 8];
            f16* lb = &Bs[(i * 256 + wid * 64) * 8];
            __builtin_amdgcn_global_load_lds((const GAS void*)ga, (LAS void*)la, 16, 0, 0);
            __builtin_amdgcn_global_load_lds((const GAS void*)gb, (LAS void*)lb, 16, 0, 0);
        }
        __syncthreads();
        #pragma unroll
        for (int ks = 0; ks < 2; ++ks) {
            f16x8 af[4], bfr[4];
            #pragma unroll
            for (int m = 0; m < 4; ++m) {
                int row = wr * 64 + m * 16 + l15;
                int kc  = (ks * 4 + l4) ^ (row & 7);
                af[m] = *(const f16x8*)(&As[row * 64 + kc * 8]);
            }
            #pragma unroll
            for (int n = 0; n < 4; ++n) {
                int row = wc * 64 + n * 16 + l15;
                int kc  = (ks * 4 + l4) ^ (row & 7);
                bfr[n] = *(const f16x8*)(&Bs[row * 64 + kc * 8]);
            }
            #pragma unroll
            for (int m = 0; m < 4; ++m)
                #pragma unroll
                for (int n = 0; n < 4; ++n)
                    acc[m][n] = __builtin_amdgcn_mfma_f32_16x16x32_f16(af[m], bfr[n], acc[m][n], 0, 0, 0);
        }
        __syncthreads();
    }

    // epilogue; D layout: col = lane&15, row = (lane>>4)*4 + r  (m89-verified)
    #pragma unroll
    for (int n = 0; n < 4; ++n) {
        int gcol = n0 + wc * 64 + n * 16 + l15;
        float bias_v = bias[gcol];
        #pragma unroll
        for (int m = 0; m < 4; ++m) {
            int grow0 = m0 + wr * 64 + m * 16 + l4 * 4;
            #pragma unroll
            for (int r = 0; r < 4; ++r) {
                int grow = grow0 + r;
                float v = acc[m][n][r] + bias_v;
                if constexpr (QKV) {
                    int b = grow >> 11, lp = grow & (LSEQ - 1);
                    int h = gcol >> 6,  d  = gcol & (DH - 1);
                    int bh = b * NH + h;
                    if (z == 0)       // Q, pre-scaled by 1/sqrt(Dh) (exact pow2)
                        out_q[((size_t)bh * LSEQ + lp) * DH + d] = (f16)(v * 0.125f);
                    else if (z == 1)  // K: [bh][l][d]
                        out_k[((size_t)bh * LSEQ + lp) * DH + d] = (f16)v;
                    else              // V transposed: [bh][d][l]
                        out_vt[((size_t)bh * DH + d) * LSEQ + lp] = (f16)v;
                } else {
                    out_f[(size_t)grow * DM + gcol] = v;
                }
            }
        }
    }
}

// ---------------------------------------------------------------- windowed attention
// block: (64 queries of one bh), 4 waves x 16 queries; key window = 192 wide
__global__ __launch_bounds__(256) void attn_kernel(const f16* __restrict__ Qb,
                                                   const f16* __restrict__ Kb,
                                                   const f16* __restrict__ Vt,
                                                   f16* __restrict__ Ob) {
    const int bh     = blockIdx.y;
    const int q0blk  = blockIdx.x * 64;
    const int wid    = threadIdx.x >> 6;
    const int lane   = threadIdx.x & 63;
    const int l15    = lane & 15, l4 = lane >> 4;
    const int qbase  = q0blk + wid * 16;
    const int kstart = q0blk - WIN;

    const f16* __restrict__ Q = Qb + (size_t)bh * LSEQ * DH;
    const f16* __restrict__ K = Kb + (size_t)bh * LSEQ * DH;
    const f16* __restrict__ V = Vt + (size_t)bh * DH * LSEQ;

    __shared__ f16 Pl[4][16][232];   // 232*2B = 464B row stride: 16B-aligned, bank-spread

    // Q fragments (A operand): row = l15, k = ks*32 + l4*8 + i
    f16x8 qf[2];
    #pragma unroll
    for (int ks = 0; ks < 2; ++ks)
        qf[ks] = *(const f16x8*)(Q + (size_t)(qbase + l15) * DH + ks * 32 + l4 * 8);

    // S = Q K^T : 12 n-tiles of 16 keys
    floatx4 sc[12] = {};
    #pragma unroll
    for (int nt = 0; nt < 12; ++nt) {
        int key = kstart + nt * 16 + l15;
        int kcl = key < 0 ? 0 : (key > LSEQ - 1 ? LSEQ - 1 : key);
        #pragma unroll
        for (int ks = 0; ks < 2; ++ks) {
            f16x8 kf = *(const f16x8*)(K + (size_t)kcl * DH + ks * 32 + l4 * 8);
            sc[nt] = __builtin_amdgcn_mfma_f32_16x16x32_f16(qf[ks], kf, sc[nt], 0, 0, 0);
        }
    }

    // mask + softmax. Row q = qbase + l4*4 + r lives in the 16 lanes sharing l4.
    float mx[4] = {-1e30f, -1e30f, -1e30f, -1e30f};
    #pragma unroll
    for (int nt = 0; nt < 12; ++nt) {
        int key = kstart + nt * 16 + l15;
        #pragma unroll
        for (int r = 0; r < 4; ++r) {
            int q = qbase + l4 * 4 + r;
            int dist = key - q; dist = dist < 0 ? -dist : dist;
            bool valid = (key >= 0) && (key < LSEQ) && (dist <= WIN);
            float s = valid ? sc[nt][r] : -1e30f;
            sc[nt][r] = s;
            mx[r] = fmaxf(mx[r], s);
        }
    }
    #pragma unroll
    for (int r = 0; r < 4; ++r)
        #pragma unroll
        for (int m = 1; m < 16; m <<= 1)
            mx[r] = fmaxf(mx[r], __shfl_xor(mx[r], m, 64));
    float sm[4] = {0.f, 0.f, 0.f, 0.f};
    #pragma unroll
    for (int nt = 0; nt < 12; ++nt)
        #pragma unroll
        for (int r = 0; r < 4; ++r) {
            float p = __expf(sc[nt][r] - mx[r]);
            sc[nt][r] = p;
            sm[r] += p;
        }
    #pragma unroll
    for (int r = 0; r < 4; ++r) {
        #pragma unroll
        for (int m = 1; m < 16; m <<= 1)
            sm[r] += __shfl_xor(sm[r], m, 64);
        sm[r] = 1.f / sm[r];
    }

    // P -> LDS in A-fragment-friendly layout
    #pragma unroll
    for (int nt = 0; nt < 12; ++nt)
        #pragma unroll
        for (int r = 0; r < 4; ++r)
            Pl[wid][l4 * 4 + r][nt * 16 + l15] = (f16)(sc[nt][r] * sm[r]);
    __syncthreads();

    // O = P V : A-frag from LDS (contiguous), B-frag from Vt (contiguous keys)
    floatx4 oc[4] = {};
    #pragma unroll
    for (int ks = 0; ks < 6; ++ks) {
        f16x8 pf = *(const f16x8*)(&Pl[wid][l15][ks * 32 + l4 * 8]);
        int kb0 = kstart + ks * 32 + l4 * 8;
        int kbc = (kb0 < 0 || kb0 > LSEQ - 8) ? 0 : kb0;  // whole chunk valid or P==0
        #pragma unroll
        for (int dt = 0; dt < 4; ++dt) {
            f16x8 vf = *(const f16x8*)(V + (size_t)(dt * 16 + l15) * LSEQ + kbc);
            oc[dt] = __builtin_amdgcn_mfma_f32_16x16x32_f16(pf, vf, oc[dt], 0, 0, 0);
        }
    }

    // write O in [B][L][H*64] f16 (A operand of final GEMM)
    int b = bh >> 3, h = bh & 7;
    #pragma unroll
    for (int dt = 0; dt < 4; ++dt) {
        int d = dt * 16 + l15;
        #pragma unroll
        for (int r = 0; r < 4; ++r) {
            int q = qbase + l4 * 4 + r;
            Ob[((size_t)b * LSEQ + q) * DM + h * DH + d] = (f16)oc[dt][r];
        }
    }
}

// ---------------------------------------------------------------- launch
extern "C" void kernel_launch(void* const* d_in, const int* in_sizes, int n_in,
                              void* d_out, int out_size, void* d_ws, size_t ws_size,
                              hipStream_t stream) {
    const float* x  = (const float*)d_in[0];
    const float* Wq = (const float*)d_in[1];
    const float* bq = (const float*)d_in[2];
    const float* Wk = (const float*)d_in[3];
    const float* bk = (const float*)d_in[4];
    const float* Wv = (const float*)d_in[5];
    const float* bv = (const float*)d_in[6];
    const float* Wo = (const float*)d_in[7];
    const float* bo = (const float*)d_in[8];
    float* out = (float*)d_out;

    char* ws = (char*)d_ws;
    f16* xb = (f16*)(ws);                       // 8 MB  [8192][512]
    f16* wt = (f16*)(ws + (8ull << 20));        // 2 MB  WqT,WkT,WvT,WoT
    f16* qb = (f16*)(ws + (10ull << 20));       // 8 MB  [32][2048][64], pre-scaled
    f16* kb = (f16*)(ws + (18ull << 20));       // 8 MB  [32][2048][64]
    f16* vt = (f16*)(ws + (26ull << 20));       // 8 MB  [32][64][2048]
    f16* ob = (f16*)(ws + (34ull << 20));       // 8 MB  [8192][512]

    cast_x_kernel<<<dim3(MR * DM / 4 / 256), 256, 0, stream>>>(x, xb);
    wt_kernel<<<dim3(16, 16, 4), dim3(32, 8), 0, stream>>>(Wq, Wk, Wv, Wo, wt);
    gemm_kernel<true><<<dim3(4, 64, 3), 256, 0, stream>>>(
        xb, wt, bq, bk, bv, qb, kb, vt, nullptr);
    attn_kernel<<<dim3(LSEQ / 64, 32), 256, 0, stream>>>(qb, kb, vt, ob);
    gemm_kernel<false><<<dim3(4, 64, 1), 256, 0, stream>>>(
        ob, wt + 3ull * DM * DM, bo, bo, bo, nullptr, nullptr, nullptr, out);
}

// Round 2
// 86.756 us; speedup vs baseline: 1.0724x; 1.0724x over previous
//
#include <hip/hip_runtime.h>
#include <cstdint>
#include <cstddef>

typedef _Float16 f16;
typedef f16 f16x8 __attribute__((ext_vector_type(8)));
typedef f16 f16x4 __attribute__((ext_vector_type(4)));
typedef float floatx4 __attribute__((ext_vector_type(4)));

#define GAS __attribute__((address_space(1)))
#define LAS __attribute__((address_space(3)))

static constexpr int LSEQ = 2048;
static constexpr int NH   = 8;
static constexpr int DH   = 64;
static constexpr int DM   = 512;
static constexpr int WIN  = 64;
static constexpr int MR   = 4 * LSEQ;  // 8192 rows (B*L)

// ---------------------------------------------------------------- cast x -> f16
__global__ __launch_bounds__(256) void cast_x_kernel(const float* __restrict__ x,
                                                     f16* __restrict__ xb) {
    int i = blockIdx.x * 256 + threadIdx.x;      // each thread: 4 elements
    float4 v = ((const float4*)x)[i];
    f16x4 o = { (f16)v.x, (f16)v.y, (f16)v.z, (f16)v.w };
    ((f16x4*)xb)[i] = o;
}

// ------------------------------------------------- transpose W (512x512) -> Wt f16
__global__ void wt_kernel(const float* __restrict__ Wq, const float* __restrict__ Wk,
                          const float* __restrict__ Wv, const float* __restrict__ Wo,
                          f16* __restrict__ wt) {
    __shared__ float tile[32][33];
    int z = blockIdx.z;
    const float* W = z == 0 ? Wq : z == 1 ? Wk : z == 2 ? Wv : Wo;
    f16* out = wt + (size_t)z * DM * DM;
    int c0 = blockIdx.x * 32, r0 = blockIdx.y * 32;
    int tx = threadIdx.x, ty = threadIdx.y;   // block (32, 8)
    #pragma unroll
    for (int i = 0; i < 32; i += 8)
        tile[ty + i][tx] = W[(size_t)(r0 + ty + i) * DM + c0 + tx];
    __syncthreads();
    #pragma unroll
    for (int i = 0; i < 32; i += 8)
        out[(size_t)(c0 + ty + i) * DM + r0 + tx] = (f16)tile[tx][ty + i];
}

// ---------------------------------------------------------------- GEMM 128x128, BK=64
// Double-buffered 2-phase pipeline (T3-minimum): stage tile t+1, compute tile t,
// __syncthreads() (vmcnt(0)+barrier) drains with ~300cy of MFMA in between.
// A: [8192][512] f16 row-major.  Bt: [512][512] f16 = B^T (row = out col).
template <bool QKV>
__global__ __launch_bounds__(256, 2) void gemm_kernel(
    const f16* __restrict__ A, const f16* __restrict__ Bt_base,
    const float* __restrict__ b0, const float* __restrict__ b1,
    const float* __restrict__ b2,
    f16* __restrict__ out_q, f16* __restrict__ out_k, f16* __restrict__ out_vt,
    float* __restrict__ out_f) {
    const int z = QKV ? blockIdx.z : 0;
    const f16* __restrict__ Bt = Bt_base + (size_t)z * (DM * DM);
    const float* __restrict__ bias = QKV ? (z == 0 ? b0 : z == 1 ? b1 : b2) : b0;

    __shared__ f16 As[2][128 * 64];
    __shared__ f16 Bs[2][128 * 64];

    const int tid  = threadIdx.x;
    const int wid  = tid >> 6;
    const int lane = tid & 63;
    const int l15  = lane & 15;
    const int l4   = lane >> 4;
    const int m0   = blockIdx.y * 128;
    const int n0   = blockIdx.x * 128;
    const int wr   = wid >> 1, wc = wid & 1;

    floatx4 acc[4][4] = {};

    // staging geometry (per thread, hoisted): chunk c = i*256 + wid*64 + lane
    // row = c>>3, col-word cw = c&7, XOR-swizzled source (rule #21), linear LDS dest.
    int c_     = wid * 64 + lane;
    int row_   = c_ >> 3, cw_ = c_ & 7;
    int cs_    = cw_ ^ (row_ & 7);

    auto stage = [&](int buf, int k0) {
        #pragma unroll
        for (int i = 0; i < 4; ++i) {
            int row = row_ + i * 32;
            int cs  = cw_ ^ (row & 7);
            const f16* ga = A  + (size_t)(m0 + row) * DM + k0 + cs * 8;
            const f16* gb = Bt + (size_t)(n0 + row) * DM + k0 + cs * 8;
            f16* la = &As[buf][(i * 256 + wid * 64 + lane) * 8 - lane * 8 + lane * 8];
            // linear dest: chunk index * 8 halves
            la = &As[buf][(i * 256 + wid * 64) * 8];
            f16* lb = &Bs[buf][(i * 256 + wid * 64) * 8];
            __builtin_amdgcn_global_load_lds((const GAS void*)ga, (LAS void*)la, 16, 0, 0);
            __builtin_amdgcn_global_load_lds((const GAS void*)gb, (LAS void*)lb, 16, 0, 0);
        }
    };
    auto compute = [&](int buf) {
        #pragma unroll
        for (int ks = 0; ks < 2; ++ks) {
            f16x8 af[4], bfr[4];
            #pragma unroll
            for (int m = 0; m < 4; ++m) {
                int row = wr * 64 + m * 16 + l15;
                int kc  = (ks * 4 + l4) ^ (row & 7);
                af[m] = *(const f16x8*)(&As[buf][row * 64 + kc * 8]);
            }
            #pragma unroll
            for (int n = 0; n < 4; ++n) {
                int row = wc * 64 + n * 16 + l15;
                int kc  = (ks * 4 + l4) ^ (row & 7);
                bfr[n] = *(const f16x8*)(&Bs[buf][row * 64 + kc * 8]);
            }
            #pragma unroll
            for (int m = 0; m < 4; ++m)
                #pragma unroll
                for (int n = 0; n < 4; ++n)
                    acc[m][n] = __builtin_amdgcn_mfma_f32_16x16x32_f16(af[m], bfr[n], acc[m][n], 0, 0, 0);
        }
    };

    stage(0, 0);
    __syncthreads();
    #pragma unroll
    for (int t = 0; t < 8; ++t) {
        if (t < 7) stage((t + 1) & 1, (t + 1) * 64);
        compute(t & 1);
        if (t < 7) __syncthreads();
    }

    // epilogue; D layout: col = lane&15, row = (lane>>4)*4 + r  (m89-verified)
    #pragma unroll
    for (int n = 0; n < 4; ++n) {
        int gcol = n0 + wc * 64 + n * 16 + l15;
        float bias_v = bias[gcol];
        #pragma unroll
        for (int m = 0; m < 4; ++m) {
            int grow0 = m0 + wr * 64 + m * 16 + l4 * 4;
            #pragma unroll
            for (int r = 0; r < 4; ++r) {
                int grow = grow0 + r;
                float v = acc[m][n][r] + bias_v;
                if constexpr (QKV) {
                    int b = grow >> 11, lp = grow & (LSEQ - 1);
                    int h = gcol >> 6,  d  = gcol & (DH - 1);
                    int bh = b * NH + h;
                    if (z == 0)       // Q, pre-scaled by 1/sqrt(Dh) (exact pow2)
                        out_q[((size_t)bh * LSEQ + lp) * DH + d] = (f16)(v * 0.125f);
                    else if (z == 1)  // K: [bh][l][d]
                        out_k[((size_t)bh * LSEQ + lp) * DH + d] = (f16)v;
                    else              // V transposed: [bh][d][l]
                        out_vt[((size_t)bh * DH + d) * LSEQ + lp] = (f16)v;
                } else {
                    out_f[(size_t)grow * DM + gcol] = v;
                }
            }
        }
    }
}

// ---------------------------------------------------------------- windowed attention
// block: (64 queries of one bh), 4 waves x 16 queries; key window = 192 wide
__global__ __launch_bounds__(256) void attn_kernel(const f16* __restrict__ Qb,
                                                   const f16* __restrict__ Kb,
                                                   const f16* __restrict__ Vt,
                                                   f16* __restrict__ Ob) {
    const int bh     = blockIdx.y;
    const int q0blk  = blockIdx.x * 64;
    const int wid    = threadIdx.x >> 6;
    const int lane   = threadIdx.x & 63;
    const int l15    = lane & 15, l4 = lane >> 4;
    const int qbase  = q0blk + wid * 16;
    const int kstart = q0blk - WIN;

    const f16* __restrict__ Q = Qb + (size_t)bh * LSEQ * DH;
    const f16* __restrict__ K = Kb + (size_t)bh * LSEQ * DH;
    const f16* __restrict__ V = Vt + (size_t)bh * DH * LSEQ;

    __shared__ f16 Pl[4][16][232];   // 232*2B = 464B row stride: 16B-aligned, bank-spread

    // Q fragments (A operand): row = l15, k = ks*32 + l4*8 + i
    f16x8 qf[2];
    #pragma unroll
    for (int ks = 0; ks < 2; ++ks)
        qf[ks] = *(const f16x8*)(Q + (size_t)(qbase + l15) * DH + ks * 32 + l4 * 8);

    // S = Q K^T : 12 n-tiles of 16 keys
    floatx4 sc[12] = {};
    #pragma unroll
    for (int nt = 0; nt < 12; ++nt) {
        int key = kstart + nt * 16 + l15;
        int kcl = key < 0 ? 0 : (key > LSEQ - 1 ? LSEQ - 1 : key);
        #pragma unroll
        for (int ks = 0; ks < 2; ++ks) {
            f16x8 kf = *(const f16x8*)(K + (size_t)kcl * DH + ks * 32 + l4 * 8);
            sc[nt] = __builtin_amdgcn_mfma_f32_16x16x32_f16(qf[ks], kf, sc[nt], 0, 0, 0);
        }
    }

    // mask + softmax. Row q = qbase + l4*4 + r lives in the 16 lanes sharing l4.
    float mx[4] = {-1e30f, -1e30f, -1e30f, -1e30f};
    #pragma unroll
    for (int nt = 0; nt < 12; ++nt) {
        int key = kstart + nt * 16 + l15;
        #pragma unroll
        for (int r = 0; r < 4; ++r) {
            int q = qbase + l4 * 4 + r;
            int dist = key - q; dist = dist < 0 ? -dist : dist;
            bool valid = (key >= 0) && (key < LSEQ) && (dist <= WIN);
            float s = valid ? sc[nt][r] : -1e30f;
            sc[nt][r] = s;
            mx[r] = fmaxf(mx[r], s);
        }
    }
    #pragma unroll
    for (int r = 0; r < 4; ++r)
        #pragma unroll
        for (int m = 1; m < 16; m <<= 1)
            mx[r] = fmaxf(mx[r], __shfl_xor(mx[r], m, 64));
    float sm[4] = {0.f, 0.f, 0.f, 0.f};
    #pragma unroll
    for (int nt = 0; nt < 12; ++nt)
        #pragma unroll
        for (int r = 0; r < 4; ++r) {
            float p = __expf(sc[nt][r] - mx[r]);
            sc[nt][r] = p;
            sm[r] += p;
        }
    #pragma unroll
    for (int r = 0; r < 4; ++r) {
        #pragma unroll
        for (int m = 1; m < 16; m <<= 1)
            sm[r] += __shfl_xor(sm[r], m, 64);
        sm[r] = 1.f / sm[r];
    }

    // P -> LDS in A-fragment-friendly layout
    #pragma unroll
    for (int nt = 0; nt < 12; ++nt)
        #pragma unroll
        for (int r = 0; r < 4; ++r)
            Pl[wid][l4 * 4 + r][nt * 16 + l15] = (f16)(sc[nt][r] * sm[r]);
    __syncthreads();

    // O = P V : A-frag from LDS (contiguous), B-frag from Vt (contiguous keys)
    floatx4 oc[4] = {};
    #pragma unroll
    for (int ks = 0; ks < 6; ++ks) {
        f16x8 pf = *(const f16x8*)(&Pl[wid][l15][ks * 32 + l4 * 8]);
        int kb0 = kstart + ks * 32 + l4 * 8;
        int kbc = (kb0 < 0 || kb0 > LSEQ - 8) ? 0 : kb0;  // whole chunk valid or P==0
        #pragma unroll
        for (int dt = 0; dt < 4; ++dt) {
            f16x8 vf = *(const f16x8*)(V + (size_t)(dt * 16 + l15) * LSEQ + kbc);
            oc[dt] = __builtin_amdgcn_mfma_f32_16x16x32_f16(pf, vf, oc[dt], 0, 0, 0);
        }
    }

    // write O in [B][L][H*64] f16 (A operand of final GEMM)
    int b = bh >> 3, h = bh & 7;
    #pragma unroll
    for (int dt = 0; dt < 4; ++dt) {
        int d = dt * 16 + l15;
        #pragma unroll
        for (int r = 0; r < 4; ++r) {
            int q = qbase + l4 * 4 + r;
            Ob[((size_t)b * LSEQ + q) * DM + h * DH + d] = (f16)oc[dt][r];
        }
    }
}

// ---------------------------------------------------------------- launch
extern "C" void kernel_launch(void* const* d_in, const int* in_sizes, int n_in,
                              void* d_out, int out_size, void* d_ws, size_t ws_size,
                              hipStream_t stream) {
    const float* x  = (const float*)d_in[0];
    const float* Wq = (const float*)d_in[1];
    const float* bq = (const float*)d_in[2];
    const float* Wk = (const float*)d_in[3];
    const float* bk = (const float*)d_in[4];
    const float* Wv = (const float*)d_in[5];
    const float* bv = (const float*)d_in[6];
    const float* Wo = (const float*)d_in[7];
    const float* bo = (const float*)d_in[8];
    float* out = (float*)d_out;

    char* ws = (char*)d_ws;
    f16* xb = (f16*)(ws);                       // 8 MB  [8192][512]
    f16* wt = (f16*)(ws + (8ull << 20));        // 2 MB  WqT,WkT,WvT,WoT
    f16* qb = (f16*)(ws + (10ull << 20));       // 8 MB  [32][2048][64], pre-scaled
    f16* kb = (f16*)(ws + (18ull << 20));       // 8 MB  [32][2048][64]
    f16* vt = (f16*)(ws + (26ull << 20));       // 8 MB  [32][64][2048]
    f16* ob = (f16*)(ws + (34ull << 20));       // 8 MB  [8192][512]

    cast_x_kernel<<<dim3(MR * DM / 4 / 256), 256, 0, stream>>>(x, xb);
    wt_kernel<<<dim3(16, 16, 4), dim3(32, 8), 0, stream>>>(Wq, Wk, Wv, Wo, wt);
    gemm_kernel<true><<<dim3(4, 64, 3), 256, 0, stream>>>(
        xb, wt, bq, bk, bv, qb, kb, vt, nullptr);
    attn_kernel<<<dim3(LSEQ / 64, 32), 256, 0, stream>>>(qb, kb, vt, ob);
    gemm_kernel<false><<<dim3(4, 64, 1), 256, 0, stream>>>(
        ob, wt + 3ull * DM * DM, bo, bo, bo, nullptr, nullptr, nullptr, out);
}

// Round 3
// 86.048 us; speedup vs baseline: 1.0812x; 1.0082x over previous
//
#include <hip/hip_runtime.h>
#include <cstdint>
#include <cstddef>

typedef _Float16 f16;
typedef f16 f16x8 __attribute__((ext_vector_type(8)));
typedef f16 f16x4 __attribute__((ext_vector_type(4)));
typedef float floatx4 __attribute__((ext_vector_type(4)));

#define GAS __attribute__((address_space(1)))
#define LAS __attribute__((address_space(3)))

static constexpr int LSEQ = 2048;
static constexpr int NH   = 8;
static constexpr int DH   = 64;
static constexpr int DM   = 512;
static constexpr int WIN  = 64;
static constexpr int MR   = 4 * LSEQ;  // 8192 rows (B*L)

// ---------------------------------------------------------------- cast x -> f16
__global__ __launch_bounds__(256) void cast_x_kernel(const float* __restrict__ x,
                                                     f16* __restrict__ xb) {
    int i = blockIdx.x * 256 + threadIdx.x;      // each thread: 4 elements
    float4 v = ((const float4*)x)[i];
    f16x4 o = { (f16)v.x, (f16)v.y, (f16)v.z, (f16)v.w };
    ((f16x4*)xb)[i] = o;
}

// ------------------------------------------------- transpose W (512x512) -> Wt f16
__global__ void wt_kernel(const float* __restrict__ Wq, const float* __restrict__ Wk,
                          const float* __restrict__ Wv, const float* __restrict__ Wo,
                          f16* __restrict__ wt) {
    __shared__ float tile[32][33];
    int z = blockIdx.z;
    const float* W = z == 0 ? Wq : z == 1 ? Wk : z == 2 ? Wv : Wo;
    f16* out = wt + (size_t)z * DM * DM;
    int c0 = blockIdx.x * 32, r0 = blockIdx.y * 32;
    int tx = threadIdx.x, ty = threadIdx.y;   // block (32, 8)
    #pragma unroll
    for (int i = 0; i < 32; i += 8)
        tile[ty + i][tx] = W[(size_t)(r0 + ty + i) * DM + c0 + tx];
    __syncthreads();
    #pragma unroll
    for (int i = 0; i < 32; i += 8)
        out[(size_t)(c0 + ty + i) * DM + r0 + tx] = (f16)tile[tx][ty + i];
}

// ---------------------------------------------------------------- GEMM 128x128, BK=64
// Counted-vmcnt double-buffered pipeline (T3+T4): prefetch for tile t+1 stays in
// flight ACROSS the raw s_barrier; only the last tile drains vmcnt(0).
// Per-wave stage() = 8 global_load_lds -> steady-state wait is vmcnt(8).
// A: [8192][512] f16 row-major.  Bt: [512][512] f16 = B^T (row = out col).
template <bool QKV>
__global__ __launch_bounds__(256, 2) void gemm_kernel(
    const f16* __restrict__ A, const f16* __restrict__ Bt_base,
    const float* __restrict__ b0, const float* __restrict__ b1,
    const float* __restrict__ b2,
    f16* __restrict__ out_q, f16* __restrict__ out_k, f16* __restrict__ out_vt,
    float* __restrict__ out_f) {
    const int z = QKV ? blockIdx.z : 0;
    const f16* __restrict__ Bt = Bt_base + (size_t)z * (DM * DM);
    const float* __restrict__ bias = QKV ? (z == 0 ? b0 : z == 1 ? b1 : b2) : b0;

    __shared__ f16 As[2][128 * 64];
    __shared__ f16 Bs[2][128 * 64];

    const int tid  = threadIdx.x;
    const int wid  = tid >> 6;
    const int lane = tid & 63;
    const int l15  = lane & 15;
    const int l4   = lane >> 4;
    const int m0   = blockIdx.y * 128;
    const int n0   = blockIdx.x * 128;
    const int wr   = wid >> 1, wc = wid & 1;

    floatx4 acc[4][4] = {};

    const int c_ = wid * 64 + lane;   // base chunk id (0..255)

    // XOR-swizzled SOURCE + linear LDS dest (rule #21); dest is wave-uniform base,
    // HW places lane i at base + i*16B.
    auto stage = [&](int buf, int k0) {
        #pragma unroll
        for (int i = 0; i < 4; ++i) {
            int c   = i * 256 + c_;
            int row = c >> 3, cw = c & 7;
            int cs  = cw ^ (row & 7);
            const f16* ga = A  + (size_t)(m0 + row) * DM + k0 + cs * 8;
            const f16* gb = Bt + (size_t)(n0 + row) * DM + k0 + cs * 8;
            f16* la = &As[buf][(i * 256 + wid * 64) * 8];
            f16* lb = &Bs[buf][(i * 256 + wid * 64) * 8];
            __builtin_amdgcn_global_load_lds((const GAS void*)ga, (LAS void*)la, 16, 0, 0);
            __builtin_amdgcn_global_load_lds((const GAS void*)gb, (LAS void*)lb, 16, 0, 0);
        }
    };
    auto compute = [&](int buf) {
        #pragma unroll
        for (int ks = 0; ks < 2; ++ks) {
            f16x8 af[4], bfr[4];
            #pragma unroll
            for (int m = 0; m < 4; ++m) {
                int row = wr * 64 + m * 16 + l15;
                int kc  = (ks * 4 + l4) ^ (row & 7);
                af[m] = *(const f16x8*)(&As[buf][row * 64 + kc * 8]);
            }
            #pragma unroll
            for (int n = 0; n < 4; ++n) {
                int row = wc * 64 + n * 16 + l15;
                int kc  = (ks * 4 + l4) ^ (row & 7);
                bfr[n] = *(const f16x8*)(&Bs[buf][row * 64 + kc * 8]);
            }
            #pragma unroll
            for (int m = 0; m < 4; ++m)
                #pragma unroll
                for (int n = 0; n < 4; ++n)
                    acc[m][n] = __builtin_amdgcn_mfma_f32_16x16x32_f16(af[m], bfr[n], acc[m][n], 0, 0, 0);
        }
    };

    stage(0, 0);
    stage(1, 64);
    #pragma unroll
    for (int t = 0; t < 8; ++t) {
        // buffer-t's 8 loads are the oldest outstanding; leave t+1's 8 in flight.
        if (t < 7) asm volatile("s_waitcnt vmcnt(8)" ::: "memory");
        else       asm volatile("s_waitcnt vmcnt(0)" ::: "memory");
        __builtin_amdgcn_sched_barrier(0);
        __builtin_amdgcn_s_barrier();      // all waves' buffer-t loads landed
        __builtin_amdgcn_sched_barrier(0);
        compute(t & 1);
        if (t < 6) {
            __builtin_amdgcn_s_barrier();  // everyone done reading buf t&1
            __builtin_amdgcn_sched_barrier(0);
            stage(t & 1, (t + 2) * 64);    // overwrite it with tile t+2
        }
    }

    // epilogue; D layout: col = lane&15, row = (lane>>4)*4 + r  (m89-verified)
    #pragma unroll
    for (int n = 0; n < 4; ++n) {
        int gcol = n0 + wc * 64 + n * 16 + l15;
        float bias_v = bias[gcol];
        #pragma unroll
        for (int m = 0; m < 4; ++m) {
            int grow0 = m0 + wr * 64 + m * 16 + l4 * 4;
            #pragma unroll
            for (int r = 0; r < 4; ++r) {
                int grow = grow0 + r;
                float v = acc[m][n][r] + bias_v;
                if constexpr (QKV) {
                    int b = grow >> 11, lp = grow & (LSEQ - 1);
                    int h = gcol >> 6,  d  = gcol & (DH - 1);
                    int bh = b * NH + h;
                    if (z == 0)       // Q, pre-scaled by 1/sqrt(Dh) (exact pow2)
                        out_q[((size_t)bh * LSEQ + lp) * DH + d] = (f16)(v * 0.125f);
                    else if (z == 1)  // K: [bh][l][d]
                        out_k[((size_t)bh * LSEQ + lp) * DH + d] = (f16)v;
                    else              // V transposed: [bh][d][l]
                        out_vt[((size_t)bh * DH + d) * LSEQ + lp] = (f16)v;
                } else {
                    out_f[(size_t)grow * DM + gcol] = v;
                }
            }
        }
    }
}

// ---------------------------------------------------------------- windowed attention
// block: (64 queries of one bh), 4 waves x 16 queries; key window = 192 wide
__global__ __launch_bounds__(256) void attn_kernel(const f16* __restrict__ Qb,
                                                   const f16* __restrict__ Kb,
                                                   const f16* __restrict__ Vt,
                                                   f16* __restrict__ Ob) {
    const int bh     = blockIdx.y;
    const int q0blk  = blockIdx.x * 64;
    const int wid    = threadIdx.x >> 6;
    const int lane   = threadIdx.x & 63;
    const int l15    = lane & 15, l4 = lane >> 4;
    const int qbase  = q0blk + wid * 16;
    const int kstart = q0blk - WIN;

    const f16* __restrict__ Q = Qb + (size_t)bh * LSEQ * DH;
    const f16* __restrict__ K = Kb + (size_t)bh * LSEQ * DH;
    const f16* __restrict__ V = Vt + (size_t)bh * DH * LSEQ;

    __shared__ f16 Pl[4][16][232];   // 232*2B = 464B row stride: 16B-aligned, bank-spread

    // Q fragments (A operand): row = l15, k = ks*32 + l4*8 + i
    f16x8 qf[2];
    #pragma unroll
    for (int ks = 0; ks < 2; ++ks)
        qf[ks] = *(const f16x8*)(Q + (size_t)(qbase + l15) * DH + ks * 32 + l4 * 8);

    // S = Q K^T : 12 n-tiles of 16 keys
    floatx4 sc[12] = {};
    #pragma unroll
    for (int nt = 0; nt < 12; ++nt) {
        int key = kstart + nt * 16 + l15;
        int kcl = key < 0 ? 0 : (key > LSEQ - 1 ? LSEQ - 1 : key);
        #pragma unroll
        for (int ks = 0; ks < 2; ++ks) {
            f16x8 kf = *(const f16x8*)(K + (size_t)kcl * DH + ks * 32 + l4 * 8);
            sc[nt] = __builtin_amdgcn_mfma_f32_16x16x32_f16(qf[ks], kf, sc[nt], 0, 0, 0);
        }
    }

    // mask + softmax. Row q = qbase + l4*4 + r lives in the 16 lanes sharing l4.
    float mx[4] = {-1e30f, -1e30f, -1e30f, -1e30f};
    #pragma unroll
    for (int nt = 0; nt < 12; ++nt) {
        int key = kstart + nt * 16 + l15;
        #pragma unroll
        for (int r = 0; r < 4; ++r) {
            int q = qbase + l4 * 4 + r;
            int dist = key - q; dist = dist < 0 ? -dist : dist;
            bool valid = (key >= 0) && (key < LSEQ) && (dist <= WIN);
            float s = valid ? sc[nt][r] : -1e30f;
            sc[nt][r] = s;
            mx[r] = fmaxf(mx[r], s);
        }
    }
    #pragma unroll
    for (int r = 0; r < 4; ++r)
        #pragma unroll
        for (int m = 1; m < 16; m <<= 1)
            mx[r] = fmaxf(mx[r], __shfl_xor(mx[r], m, 64));
    float sm[4] = {0.f, 0.f, 0.f, 0.f};
    #pragma unroll
    for (int nt = 0; nt < 12; ++nt)
        #pragma unroll
        for (int r = 0; r < 4; ++r) {
            float p = __expf(sc[nt][r] - mx[r]);
            sc[nt][r] = p;
            sm[r] += p;
        }
    #pragma unroll
    for (int r = 0; r < 4; ++r) {
        #pragma unroll
        for (int m = 1; m < 16; m <<= 1)
            sm[r] += __shfl_xor(sm[r], m, 64);
        sm[r] = 1.f / sm[r];
    }

    // P -> LDS in A-fragment-friendly layout
    #pragma unroll
    for (int nt = 0; nt < 12; ++nt)
        #pragma unroll
        for (int r = 0; r < 4; ++r)
            Pl[wid][l4 * 4 + r][nt * 16 + l15] = (f16)(sc[nt][r] * sm[r]);
    __syncthreads();

    // O = P V : A-frag from LDS (contiguous), B-frag from Vt (contiguous keys)
    floatx4 oc[4] = {};
    #pragma unroll
    for (int ks = 0; ks < 6; ++ks) {
        f16x8 pf = *(const f16x8*)(&Pl[wid][l15][ks * 32 + l4 * 8]);
        int kb0 = kstart + ks * 32 + l4 * 8;
        int kbc = (kb0 < 0 || kb0 > LSEQ - 8) ? 0 : kb0;  // whole chunk valid or P==0
        #pragma unroll
        for (int dt = 0; dt < 4; ++dt) {
            f16x8 vf = *(const f16x8*)(V + (size_t)(dt * 16 + l15) * LSEQ + kbc);
            oc[dt] = __builtin_amdgcn_mfma_f32_16x16x32_f16(pf, vf, oc[dt], 0, 0, 0);
        }
    }

    // write O in [B][L][H*64] f16 (A operand of final GEMM)
    int b = bh >> 3, h = bh & 7;
    #pragma unroll
    for (int dt = 0; dt < 4; ++dt) {
        int d = dt * 16 + l15;
        #pragma unroll
        for (int r = 0; r < 4; ++r) {
            int q = qbase + l4 * 4 + r;
            Ob[((size_t)b * LSEQ + q) * DM + h * DH + d] = (f16)oc[dt][r];
        }
    }
}

// ---------------------------------------------------------------- launch
extern "C" void kernel_launch(void* const* d_in, const int* in_sizes, int n_in,
                              void* d_out, int out_size, void* d_ws, size_t ws_size,
                              hipStream_t stream) {
    const float* x  = (const float*)d_in[0];
    const float* Wq = (const float*)d_in[1];
    const float* bq = (const float*)d_in[2];
    const float* Wk = (const float*)d_in[3];
    const float* bk = (const float*)d_in[4];
    const float* Wv = (const float*)d_in[5];
    const float* bv = (const float*)d_in[6];
    const float* Wo = (const float*)d_in[7];
    const float* bo = (const float*)d_in[8];
    float* out = (float*)d_out;

    char* ws = (char*)d_ws;
    f16* xb = (f16*)(ws);                       // 8 MB  [8192][512]
    f16* wt = (f16*)(ws + (8ull << 20));        // 2 MB  WqT,WkT,WvT,WoT
    f16* qb = (f16*)(ws + (10ull << 20));       // 8 MB  [32][2048][64], pre-scaled
    f16* kb = (f16*)(ws + (18ull << 20));       // 8 MB  [32][2048][64]
    f16* vt = (f16*)(ws + (26ull << 20));       // 8 MB  [32][64][2048]
    f16* ob = (f16*)(ws + (34ull << 20));       // 8 MB  [8192][512]

    cast_x_kernel<<<dim3(MR * DM / 4 / 256), 256, 0, stream>>>(x, xb);
    wt_kernel<<<dim3(16, 16, 4), dim3(32, 8), 0, stream>>>(Wq, Wk, Wv, Wo, wt);
    gemm_kernel<true><<<dim3(4, 64, 3), 256, 0, stream>>>(
        xb, wt, bq, bk, bv, qb, kb, vt, nullptr);
    attn_kernel<<<dim3(LSEQ / 64, 32), 256, 0, stream>>>(qb, kb, vt, ob);
    gemm_kernel<false><<<dim3(4, 64, 1), 256, 0, stream>>>(
        ob, wt + 3ull * DM * DM, bo, bo, bo, nullptr, nullptr, nullptr, out);
}